// Round 8
// baseline (2346.158 us; speedup 1.0000x reference)
//
#include <hip/hip_runtime.h>
#include <math.h>

typedef __bf16 bf16_t;
typedef __bf16 bf16x8 __attribute__((ext_vector_type(8)));
typedef float f32x4 __attribute__((ext_vector_type(4)));
typedef int i32x4 __attribute__((ext_vector_type(4)));
typedef unsigned int u32;

#define HID 2048
#define NBATCH 16
#define SEQLEN 512
#define MTOT (NBATCH * SEQLEN)
#define NBLK 32
#define RTHREADS 512
#define LN_EPS 1e-5f

// ================= GEMM: inp = x @ Wi^T + b  -> d_out (fp32) =================
__global__ __launch_bounds__(256) void gemm_proj(
    const float* __restrict__ X,
    const float* __restrict__ Wi,
    const float* __restrict__ bias,
    float* __restrict__ C,
    int* __restrict__ flags)
{
    __shared__ bf16_t lA[128 * 32];
    __shared__ bf16_t lB[128 * 32];
    const int tid = threadIdx.x;
    if (blockIdx.x == 0 && blockIdx.y == 0) {
        if (tid < NBLK) flags[tid] = 0;   // re-zero EVERY launch (graph replay safety)
    }
    const int lane = tid & 63;
    const int wv = tid >> 6;
    const int bn = blockIdx.x * 128;
    const int bm = blockIdx.y * 128;
    const int wr = (wv >> 1) * 64;
    const int wc = (wv & 1) * 64;

    f32x4 zero = {0.f, 0.f, 0.f, 0.f};
    f32x4 acc[4][4];
#pragma unroll
    for (int i = 0; i < 4; ++i)
#pragma unroll
        for (int j = 0; j < 4; ++j) acc[i][j] = zero;

    for (int k0 = 0; k0 < HID; k0 += 32) {
        __syncthreads();
#pragma unroll
        for (int c = 0; c < 2; ++c) {
            const int chunk = c * 256 + tid;      // 0..511
            const int row = chunk >> 2;           // 0..127
            const int kp = (chunk & 3) ^ (row & 3); // XOR-swizzled source chunk
            {
                const float* s = X + (size_t)(bm + row) * HID + k0 + kp * 8;
                float4 a0 = *(const float4*)s;
                float4 a1 = *(const float4*)(s + 4);
                bf16x8 v;
                v[0] = (bf16_t)a0.x; v[1] = (bf16_t)a0.y; v[2] = (bf16_t)a0.z; v[3] = (bf16_t)a0.w;
                v[4] = (bf16_t)a1.x; v[5] = (bf16_t)a1.y; v[6] = (bf16_t)a1.z; v[7] = (bf16_t)a1.w;
                *(bf16x8*)(lA + chunk * 8) = v;
            }
            {
                const float* s = Wi + (size_t)(bn + row) * HID + k0 + kp * 8;
                float4 a0 = *(const float4*)s;
                float4 a1 = *(const float4*)(s + 4);
                bf16x8 v;
                v[0] = (bf16_t)a0.x; v[1] = (bf16_t)a0.y; v[2] = (bf16_t)a0.z; v[3] = (bf16_t)a0.w;
                v[4] = (bf16_t)a1.x; v[5] = (bf16_t)a1.y; v[6] = (bf16_t)a1.z; v[7] = (bf16_t)a1.w;
                *(bf16x8*)(lB + chunk * 8) = v;
            }
        }
        __syncthreads();

        bf16x8 af[4], bfr[4];
#pragma unroll
        for (int i = 0; i < 4; ++i) {
            const int row = wr + i * 16 + (lane & 15);
            const int ck = (lane >> 4) ^ (row & 3);
            af[i] = *(const bf16x8*)(lA + row * 32 + ck * 8);
        }
#pragma unroll
        for (int j = 0; j < 4; ++j) {
            const int row = wc + j * 16 + (lane & 15);
            const int ck = (lane >> 4) ^ (row & 3);
            bfr[j] = *(const bf16x8*)(lB + row * 32 + ck * 8);
        }
#pragma unroll
        for (int i = 0; i < 4; ++i)
#pragma unroll
            for (int j = 0; j < 4; ++j)
                acc[i][j] = __builtin_amdgcn_mfma_f32_16x16x32_bf16(af[i], bfr[j], acc[i][j], 0, 0, 0);
    }

#pragma unroll
    for (int j = 0; j < 4; ++j) {
        const int col = bn + wc + j * 16 + (lane & 15);
        const float bv = bias[col];
#pragma unroll
        for (int i = 0; i < 4; ++i) {
#pragma unroll
            for (int r = 0; r < 4; ++r) {
                const int row = bm + wr + i * 16 + (lane >> 4) * 4 + r;
                C[(size_t)row * HID + col] = acc[i][j][r] + bv;
            }
        }
    }
}

// ================= Persistent recurrent kernel =================
// 32 blocks x 512 thr (8 waves). Block owns 64 output cols; wave = K-eighth
// (256 K-rows) x 64 cols -> wf[32] = 128 VGPR (NO spill, vs R7's 256+spill).
// Barriers are raw s_barrier with hand-placed counted waits:
//   P (post-poll release), L (LDS write->read, lgkmcnt only), T (tail,
//   vmcnt(0) per wave before flag publish). cin prefetch + io store issue
//   mid-iteration so no long-latency op sits in the tail drain.
// Sync protocol (R4/R7, validated): flags[32] one line; tid0 publishes t+1
// after barrier T; wave0 polls at head; state via packed-u32 relaxed agent
// stores / sc0 sc1 dwordx4 loads. Ping-pong: flag>=t => all blocks' iter-t-1
// reads done => overwriting buf(t-2) safe.
__global__ __launch_bounds__(RTHREADS, 1) void recurrent(
    const float* __restrict__ Wr,
    const float* __restrict__ mask,
    const float* __restrict__ tau,
    float* __restrict__ io,      // d_out: holds inp (read rows t+1) -> states (write row t)
    bf16_t* __restrict__ st0,
    bf16_t* __restrict__ st1,
    int* __restrict__ flags)     // [32]
{
    const int tid = threadIdx.x;
    const int lane = tid & 63;
    const int wv = tid >> 6;          // K-eighth 0..7
    const int colbase = blockIdx.x * 64;

    __shared__ float red[8][16][68];  // [kq][batch][col] pad 68

    // ---- preload masked weights: 32 MFMA B-fragments per wave (128 VGPR) ----
    bf16x8 wf[32];
    {
        const int kb = wv * 256 + (lane >> 4) * 8;
#pragma unroll
        for (int ct = 0; ct < 4; ++ct) {
            const int gc = colbase + ct * 16 + (lane & 15);
#pragma unroll
            for (int kf = 0; kf < 8; ++kf) {
                const size_t off = (size_t)gc * HID + kb + kf * 32;
                float4 a0 = *(const float4*)(Wr + off);
                float4 a1 = *(const float4*)(Wr + off + 4);
                float4 m0 = *(const float4*)(mask + off);
                float4 m1 = *(const float4*)(mask + off + 4);
                bf16x8 v;
                v[0] = (bf16_t)(a0.x * m0.x); v[1] = (bf16_t)(a0.y * m0.y);
                v[2] = (bf16_t)(a0.z * m0.z); v[3] = (bf16_t)(a0.w * m0.w);
                v[4] = (bf16_t)(a1.x * m1.x); v[5] = (bf16_t)(a1.y * m1.y);
                v[6] = (bf16_t)(a1.z * m1.z); v[7] = (bf16_t)(a1.w * m1.w);
                wf[ct * 8 + kf] = v;
            }
        }
    }

    // update mapping: 512 threads <-> 16 batches x 32 col-pairs
    const int row = tid >> 5;          // batch 0..15
    const int uc  = (tid & 31) * 2;    // col offset within block (even)
    const int gcol = colbase + uc;
    float al0, al1;
    {
        float tv0 = fminf(fmaxf(tau[gcol],     1.0f), 20.0f);
        float tv1 = fminf(fmaxf(tau[gcol + 1], 1.0f), 20.0f);
        al0 = fminf(fmaxf(0.5f / tv0, 0.0f), 1.0f);
        al1 = fminf(fmaxf(0.5f / tv1, 0.0f), 1.0f);
    }

    float s_old0 = 0.f, s_old1 = 0.f;
    float2 cin = *(const float2*)(io + (size_t)row * (SEQLEN * HID) + gcol);

    const int akb = wv * 256 + (lane >> 4) * 8;   // A-frag k offset
    bf16_t* cur = st0;
    bf16_t* nxt = st1;

    // ---- step 0: state zero -> rec = 0; store, full drain, publish ----
    {
        float z0 = fminf(fmaxf(cin.x, -15.f), 15.f);
        float z1 = fminf(fmaxf(cin.y, -15.f), 15.f);
        const float e0 = __expf(2.0f * z0), e1 = __expf(2.0f * z1);
        float sn0 = fminf(fmaxf(al0 * ((e0 - 1.0f) / (e0 + 1.0f)), -1.0f), 1.0f);
        float sn1 = fminf(fmaxf(al1 * ((e1 - 1.0f) / (e1 + 1.0f)), -1.0f), 1.0f);
        union { bf16_t b[2]; u32 u; } p;
        p.b[0] = (bf16_t)sn0; p.b[1] = (bf16_t)sn1;
        __hip_atomic_store((u32*)(nxt + (size_t)row * HID + gcol), p.u,
                           __ATOMIC_RELAXED, __HIP_MEMORY_SCOPE_AGENT);
        float2 ov; ov.x = sn0; ov.y = sn1;
        *(float2*)(io + (size_t)row * (SEQLEN * HID) + gcol) = ov;
        s_old0 = sn0; s_old1 = sn1;
        cin = *(const float2*)(io + (size_t)row * (SEQLEN * HID) + HID + gcol);
        __syncthreads();   // full drain of everyone's state stores
        if (tid == 0)
            __hip_atomic_store(flags + (int)blockIdx.x, 1,
                               __ATOMIC_RELAXED, __HIP_MEMORY_SCOPE_AGENT);
        bf16_t* tmp = cur; cur = nxt; nxt = tmp;
    }

    for (int t = 1; t < SEQLEN; ++t) {
        // ---- head: wave0 polls, others park at barrier P ----
        if (wv == 0) {
            int v;
            do {
                v = __hip_atomic_load(flags + (lane & 31),
                                      __ATOMIC_RELAXED, __HIP_MEMORY_SCOPE_AGENT);
            } while (__ballot(v < t) != 0ull);
        }
        __builtin_amdgcn_sched_barrier(0);
        asm volatile("s_barrier" ::: "memory");          // P
        __builtin_amdgcn_sched_barrier(0);

        // ---- device-coherent A-fragment loads (8 x 16B) + cin(t+1) prefetch ----
        const bf16_t* ab = cur + (size_t)(lane & 15) * HID + akb;
        union uf { i32x4 i; bf16x8 v; } a0_, a1_, a2_, a3_, a4_, a5_, a6_, a7_;
        asm volatile("global_load_dwordx4 %0, %1, off sc0 sc1"            : "=v"(a0_.i) : "v"(ab) : "memory");
        asm volatile("global_load_dwordx4 %0, %1, off offset:64 sc0 sc1"  : "=v"(a1_.i) : "v"(ab) : "memory");
        asm volatile("global_load_dwordx4 %0, %1, off offset:128 sc0 sc1" : "=v"(a2_.i) : "v"(ab) : "memory");
        asm volatile("global_load_dwordx4 %0, %1, off offset:192 sc0 sc1" : "=v"(a3_.i) : "v"(ab) : "memory");
        asm volatile("global_load_dwordx4 %0, %1, off offset:256 sc0 sc1" : "=v"(a4_.i) : "v"(ab) : "memory");
        asm volatile("global_load_dwordx4 %0, %1, off offset:320 sc0 sc1" : "=v"(a5_.i) : "v"(ab) : "memory");
        asm volatile("global_load_dwordx4 %0, %1, off offset:384 sc0 sc1" : "=v"(a6_.i) : "v"(ab) : "memory");
        asm volatile("global_load_dwordx4 %0, %1, off offset:448 sc0 sc1" : "=v"(a7_.i) : "v"(ab) : "memory");
        // prefetch next-step input (independent of flags; covered by MFMA phase)
        const int tn = (t < SEQLEN - 1) ? (t + 1) : t;
        float2 cin_next = *(const float2*)(io + (size_t)row * (SEQLEN * HID) + (size_t)tn * HID + gcol);

        f32x4 acc0 = {0.f,0.f,0.f,0.f}, acc1 = {0.f,0.f,0.f,0.f};
        f32x4 acc2 = {0.f,0.f,0.f,0.f}, acc3 = {0.f,0.f,0.f,0.f};

        asm volatile("s_waitcnt vmcnt(5)" ::: "memory");  // a0..a3 landed (cin may fly)
        __builtin_amdgcn_sched_barrier(0);
#define MF(u_, kf) \
        acc0 = __builtin_amdgcn_mfma_f32_16x16x32_bf16(u_.v, wf[kf],      acc0, 0, 0, 0); \
        acc1 = __builtin_amdgcn_mfma_f32_16x16x32_bf16(u_.v, wf[8 + kf],  acc1, 0, 0, 0); \
        acc2 = __builtin_amdgcn_mfma_f32_16x16x32_bf16(u_.v, wf[16 + kf], acc2, 0, 0, 0); \
        acc3 = __builtin_amdgcn_mfma_f32_16x16x32_bf16(u_.v, wf[24 + kf], acc3, 0, 0, 0);
        MF(a0_, 0) MF(a1_, 1) MF(a2_, 2) MF(a3_, 3)
        asm volatile("s_waitcnt vmcnt(1)" ::: "memory");  // a4..a7 landed
        __builtin_amdgcn_sched_barrier(0);
        MF(a4_, 4) MF(a5_, 5) MF(a6_, 6) MF(a7_, 7)
#undef MF

        // ---- LDS partials; barrier L needs only lgkmcnt ----
        {
            const int r0 = (lane >> 4) * 4;
            const int cA = lane & 15;
#pragma unroll
            for (int r = 0; r < 4; ++r) {
                red[wv][r0 + r][cA]      = acc0[r];
                red[wv][r0 + r][16 + cA] = acc1[r];
                red[wv][r0 + r][32 + cA] = acc2[r];
                red[wv][r0 + r][48 + cA] = acc3[r];
            }
        }
        asm volatile("s_waitcnt lgkmcnt(0)" ::: "memory");
        __builtin_amdgcn_sched_barrier(0);
        asm volatile("s_barrier" ::: "memory");          // L
        __builtin_amdgcn_sched_barrier(0);

        float rec0 = 0.f, rec1 = 0.f;
#pragma unroll
        for (int q = 0; q < 8; ++q) {
            float2 s = *(const float2*)&red[q][row][uc];
            rec0 += s.x; rec1 += s.y;
        }

        // ---- fused update ----
        float z0 = fminf(fmaxf(cin.x + rec0, -15.f), 15.f);
        float z1 = fminf(fmaxf(cin.y + rec1, -15.f), 15.f);
        const float e0 = __expf(2.0f * z0), e1 = __expf(2.0f * z1);
        const float tg0 = (e0 - 1.0f) / (e0 + 1.0f);
        const float tg1 = (e1 - 1.0f) / (e1 + 1.0f);
        float sn0 = fminf(fmaxf(s_old0 + al0 * (tg0 - s_old0), -1.0f), 1.0f);
        float sn1 = fminf(fmaxf(s_old1 + al1 * (tg1 - s_old1), -1.0f), 1.0f);

        // ---- state store (packed u32, agent write-through) + io store ----
        union { bf16_t b[2]; u32 u; } p;
        p.b[0] = (bf16_t)sn0; p.b[1] = (bf16_t)sn1;
        __hip_atomic_store((u32*)(nxt + (size_t)row * HID + gcol), p.u,
                           __ATOMIC_RELAXED, __HIP_MEMORY_SCOPE_AGENT);
        float2 ov; ov.x = sn0; ov.y = sn1;
        *(float2*)(io + (size_t)row * (SEQLEN * HID) + (size_t)t * HID + gcol) = ov;

        // ---- tail: per-wave drain -> barrier T -> publish t+1 ----
        asm volatile("s_waitcnt vmcnt(0)" ::: "memory");
        __builtin_amdgcn_sched_barrier(0);
        asm volatile("s_barrier" ::: "memory");          // T
        __builtin_amdgcn_sched_barrier(0);
        if (t != SEQLEN - 1 && tid == 0)
            __hip_atomic_store(flags + (int)blockIdx.x, t + 1,
                               __ATOMIC_RELAXED, __HIP_MEMORY_SCOPE_AGENT);

        s_old0 = sn0; s_old1 = sn1;
        cin = cin_next;
        bf16_t* tmp = cur; cur = nxt; nxt = tmp;
    }
}

// ================= LayerNorm (in-place on d_out) =================
__global__ __launch_bounds__(256) void ln_kernel(
    float* __restrict__ io,
    const float* __restrict__ gamma,
    const float* __restrict__ beta)
{
    const size_t row = blockIdx.x;
    float* p = io + row * HID;
    const int tid = threadIdx.x;
    float4 v0 = *(const float4*)(p + tid * 4);
    float4 v1 = *(const float4*)(p + 1024 + tid * 4);
    float s  = v0.x + v0.y + v0.z + v0.w + v1.x + v1.y + v1.z + v1.w;
    float ss = v0.x * v0.x + v0.y * v0.y + v0.z * v0.z + v0.w * v0.w
             + v1.x * v1.x + v1.y * v1.y + v1.z * v1.z + v1.w * v1.w;
#pragma unroll
    for (int off = 32; off > 0; off >>= 1) {
        s  += __shfl_down(s, off, 64);
        ss += __shfl_down(ss, off, 64);
    }
    __shared__ float rs[4], rss[4];
    if ((tid & 63) == 0) { rs[tid >> 6] = s; rss[tid >> 6] = ss; }
    __syncthreads();
    s  = rs[0] + rs[1] + rs[2] + rs[3];
    ss = rss[0] + rss[1] + rss[2] + rss[3];
    const float mu = s * (1.f / HID);
    const float var = ss * (1.f / HID) - mu * mu;
    const float inv = rsqrtf(var + LN_EPS);
    const int c0 = tid * 4, c1 = 1024 + tid * 4;
    float4 g0 = *(const float4*)(gamma + c0);
    float4 g1 = *(const float4*)(gamma + c1);
    float4 b0 = *(const float4*)(beta + c0);
    float4 b1 = *(const float4*)(beta + c1);
    float4 o0, o1;
    o0.x = (v0.x - mu) * inv * g0.x + b0.x;
    o0.y = (v0.y - mu) * inv * g0.y + b0.y;
    o0.z = (v0.z - mu) * inv * g0.z + b0.z;
    o0.w = (v0.w - mu) * inv * g0.w + b0.w;
    o1.x = (v1.x - mu) * inv * g1.x + b1.x;
    o1.y = (v1.y - mu) * inv * g1.y + b1.y;
    o1.z = (v1.z - mu) * inv * g1.z + b1.z;
    o1.w = (v1.w - mu) * inv * g1.w + b1.w;
    *(float4*)(p + tid * 4) = o0;
    *(float4*)(p + 1024 + tid * 4) = o1;
}

extern "C" void kernel_launch(void* const* d_in, const int* in_sizes, int n_in,
                              void* d_out, int out_size, void* d_ws, size_t ws_size,
                              hipStream_t stream)
{
    const float* x     = (const float*)d_in[0];
    const float* Wi    = (const float*)d_in[1];
    const float* bias  = (const float*)d_in[2];
    const float* Wr    = (const float*)d_in[3];
    const float* mask  = (const float*)d_in[4];
    const float* tau   = (const float*)d_in[5];
    const float* gamma = (const float*)d_in[6];
    const float* beta  = (const float*)d_in[7];
    float* out = (float*)d_out;

    bf16_t* st0 = (bf16_t*)d_ws;
    bf16_t* st1 = st0 + (size_t)NBATCH * HID;
    int* flags  = (int*)(st1 + (size_t)NBATCH * HID);

    // 1) input projection -> d_out rows hold inp[b,t,:] (fp32); also zeroes flags
    gemm_proj<<<dim3(16, 64), 256, 0, stream>>>(x, Wi, bias, out, flags);
    // 2) persistent recurrence: overwrites d_out rows with pre-LN states
    recurrent<<<NBLK, RTHREADS, 0, stream>>>(Wr, mask, tau, out, st0, st1, flags);
    // 3) layernorm in-place
    ln_kernel<<<MTOT, 256, 0, stream>>>(out, gamma, beta);
}